// Round 7
// baseline (705.532 us; speedup 1.0000x reference)
//
#include <hip/hip_runtime.h>
#include <hip/hip_bf16.h>

typedef unsigned short ushort_t;
typedef __attribute__((ext_vector_type(8))) short short8;
typedef __attribute__((ext_vector_type(4))) short short4v;
typedef __attribute__((ext_vector_type(4))) float f32x4;

// Problem constants
constexpr int Hh = 256, Ww = 256, HW = Hh * Ww;
constexpr int Bb = 2, Cc = 64, Pp = 3, NOo = 16, FEXc = 48, Nn = 32768;
constexpr int TW = 32, TH = 4;       // conv spatial tile per block
constexpr int HALOP = (TH + 2) * 34; // 204 halo pixels
constexpr int NSLOT = (HALOP + 15) / 16;   // 13 DMA slots (16 px x 32ch each)
constexpr int SROWS = NSLOT * 16;    // 208 staged rows
constexpr int PADH = 72;             // gather-MLP LDS point stride (bf16)

__device__ inline ushort_t f2bf(float v) {
    __hip_bfloat16 h = __float2bfloat16(v);
    return *(ushort_t*)&h;
}
__device__ inline float bf2f(ushort_t u) {
    __hip_bfloat16 h = *(__hip_bfloat16*)&u;
    return __bfloat162float(h);
}
// async 16B global->LDS DMA: dest = lds base (wave-uniform) + lane*16
__device__ inline void gload_lds16(const ushort_t* g, ushort_t* l) {
    __builtin_amdgcn_global_load_lds(
        (const __attribute__((address_space(1))) unsigned int*)g,
        (__attribute__((address_space(3))) unsigned int*)l, 16, 0, 0);
}

// -------- mask weight: wm = mask / max(avg3x3(mask), 1e-8); also zero the zpage ------
__global__ __launch_bounds__(256) void k_wm(const float* __restrict__ mask,
                                            float* __restrict__ wm,
                                            float* __restrict__ zpage) {
    int pos = blockIdx.x * 256 + threadIdx.x;
    if (blockIdx.x == 0 && threadIdx.x < 64) zpage[threadIdx.x] = 0.f;  // 256B zeros
    int h = pos >> 8, w = pos & 255;
    float s = 0.f;
    #pragma unroll
    for (int dy = -1; dy <= 1; ++dy)
        #pragma unroll
        for (int dx = -1; dx <= 1; ++dx) {
            int hh = h + dy, ww = w + dx;
            if (hh >= 0 && hh < Hh && ww >= 0 && ww < Ww) s += mask[hh * Ww + ww];
        }
    float avg = s * (1.f / 9.f);
    wm[pos] = mask[pos] / fmaxf(avg, 1e-8f);
}

// ---------------- zero a float4 buffer ----------------
__global__ __launch_bounds__(256) void k_zero(float4* __restrict__ p) {
    p[blockIdx.x * 256 + threadIdx.x] = make_float4(0.f, 0.f, 0.f, 0.f);
}

// ---------------- weight transforms: fp32 [oc][cin][3][3] -> bf16 [tap][oc][c64] ----
__global__ __launch_bounds__(256) void k_wx_res(const float* __restrict__ src,
                                                ushort_t* __restrict__ dst) {
    int idx = blockIdx.x * 256 + threadIdx.x;          // < 12*9*64*64 = 442368
    int j = idx / 36864; int rem = idx - j * 36864;
    int t = rem >> 12; int o = (rem >> 6) & 63; int c = rem & 63;
    dst[idx] = f2bf(src[j * 36864 + o * 576 + c * 9 + t]);
}
__global__ __launch_bounds__(256) void k_wx_out(const float* __restrict__ src,
                                                ushort_t* __restrict__ dst) {
    int idx = blockIdx.x * 256 + threadIdx.x;          // < 3*9*16*64 = 27648
    int i = idx / 9216; int rem = idx - i * 9216;
    int t = rem >> 10; int o = (rem >> 6) & 15; int c = rem & 63;
    dst[idx] = f2bf(src[i * 9216 + o * 576 + c * 9 + t]);
}
__global__ __launch_bounds__(256) void k_wx_trunk(const float* __restrict__ src,
                                                  ushort_t* __restrict__ dst) {
    int idx = blockIdx.x * 256 + threadIdx.x;          // < 4*9*48*64 = 110592
    int j = idx / 27648; int rem = idx - j * 27648;
    int t = rem / 3072; int rem2 = rem - t * 3072;
    int o = rem2 >> 6; int c = rem2 & 63;
    float v = (c < 48) ? src[j * (48 * 48 * 9) + o * 432 + c * 9 + t] : 0.f;
    dst[idx] = f2bf(v);
}
// MLP weights -> A-frag layout [out][k64] bf16, biases folded at k=49 (L1) / 48 (L2) / 49 (L3)
__global__ __launch_bounds__(256) void k_wx_mlp(
    const float* __restrict__ w1, const float* __restrict__ b1,
    const float* __restrict__ w2, const float* __restrict__ b2,
    const float* __restrict__ w3, const float* __restrict__ b3,
    ushort_t* __restrict__ dst) {
    int idx = blockIdx.x * 256 + threadIdx.x;          // < 7168
    float v = 0.f;
    if (idx < 3072) {                                  // wA1 [48][64]
        int o = idx >> 6, c = idx & 63;
        v = (c < 49) ? w1[o * 49 + c] : (c == 49 ? b1[o] : 0.f);
    } else if (idx < 6144) {                           // wA2 [48][64]
        int o = (idx - 3072) >> 6, c = idx & 63;
        v = (c < 48) ? w2[o * 48 + c] : (c == 48 ? b2[o] : 0.f);
    } else {                                           // wA3 [16][64]
        int o = (idx - 6144) >> 6, c = idx & 63;
        if (o < 3) v = (c < 48) ? w3[o * 48 + c] : (c == 49 ? b3[o] : 0.f);
    }
    dst[idx] = f2bf(v);
}

// ------- xs: NCHW fp32 -> masked NHWC bf16, all pyramids (z = i*B + b) --------------
__global__ __launch_bounds__(256) void k_xm(const float* __restrict__ xs,
                                            const float* __restrict__ mask,
                                            ushort_t* __restrict__ X) {
    __shared__ float l[64 * 65];
    const int p0 = blockIdx.x * 64;
    const size_t zoff = (size_t)blockIdx.y * 64 * HW;
    const int tid = threadIdx.x;
    const int px = tid & 63;
    const float mv = mask[p0 + px];
    #pragma unroll
    for (int k = 0; k < 16; ++k) {
        int c = (tid >> 6) + 4 * k;
        l[c * 65 + px] = xs[zoff + (size_t)c * HW + p0 + px] * mv;
    }
    __syncthreads();
    #pragma unroll
    for (int k = 0; k < 2; ++k) {
        int idx = tid + k * 256;
        int p = idx >> 3, c8 = idx & 7;
        short8 v;
        #pragma unroll
        for (int i = 0; i < 8; ++i) v[i] = (short)f2bf(l[(c8 * 8 + i) * 65 + p]);
        *(short8*)&X[zoff + (size_t)(p0 + p) * 64 + c8 * 8] = v;
    }
}

// ---------------- MFMA implicit-GEMM 3x3 conv (NHWC bf16, ch stride 64) ------------
// Two 32-channel K-phases restage the SAME 13.3KB LDS buffer. LDS row = 32ch (64B,
// 4 x 16B slots). Swizzle: slot d of pixel pp holds global ch-8 group (d^((pp>>1)&3)).
// OOB halo lanes DMA from a zero page (per-lane global source) -> exact zero padding,
// no post-DMA LDS writes, no cross-wave race.
// z = pyramid*2 + batch (trunk: z=batch, wstride=0). TOF: out -> F at chan (z>>1)*16.
// MODE 0: out = relu(conv*wm)    MODE 1: out = base + conv*wm    MODE 2: out = conv*wm
template <int OC, int MODE, bool TOF>
__global__ __launch_bounds__(256) void k_mconv(
    const ushort_t* __restrict__ in,
    const ushort_t* __restrict__ wgt, int wstride,
    const float* __restrict__ wm,
    const ushort_t* __restrict__ zp,      // >=128B of zeros, 16B aligned
    const ushort_t* __restrict__ base,
    ushort_t* __restrict__ out) {
    constexpr int NM = OC / 16;
    __shared__ __align__(1024) ushort_t lds[SROWS * 32];
    const int tid = threadIdx.x;
    const int wv = tid >> 6;
    const int ln = tid & 63;
    const int w0 = blockIdx.x * TW, h0 = blockIdx.y * TH;
    const int zz = blockIdx.z;
    const ushort_t* inb = in + (size_t)zz * HW * 64;
    const ushort_t* wB = wgt + (size_t)(zz >> 1) * wstride;
    const ushort_t* baseb = base ? base + (size_t)zz * HW * 64 : nullptr;
    ushort_t* outb = TOF ? out + (size_t)(zz & 1) * HW * 64 : out + (size_t)zz * HW * 64;
    const int ocb = TOF ? (zz >> 1) * 16 : 0;

    const int lo = ln & 15, slr = ln >> 4, g8 = slr * 8;

    f32x4 acc[NM][2];
    #pragma unroll
    for (int mf = 0; mf < NM; ++mf)
        #pragma unroll
        for (int nf = 0; nf < 2; ++nf) acc[mf][nf] = (f32x4){0.f, 0.f, 0.f, 0.f};

    #pragma unroll
    for (int h = 0; h < 2; ++h) {
        if (h) __syncthreads();            // all waves done reading phase-0 LDS
        // ---- stage 32 channels of the 34x6 halo (<=4 DMA per wave) ----
        #pragma unroll
        for (int k = 0; k < 4; ++k) {
            int s = wv + 4 * k;
            if (s < NSLOT) {
                int pp = s * 16 + (ln >> 2), d = ln & 3;
                int r = (pp * 241) >> 13;          // pp/34 for pp<208
                int col = pp - r * 34;
                int gh = h0 + r - 1, gw = w0 + col - 1;
                bool ok = (pp < HALOP) & (gh >= 0) & (gh < Hh) & (gw >= 0) & (gw < Ww);
                int ch = ((d ^ ((pp >> 1) & 3)) << 3) + h * 32;
                const ushort_t* src = ok ? inb + ((size_t)(gh * Ww + gw)) * 64 + ch
                                         : zp + ch;
                gload_lds16(src, &lds[s * 512]);
            }
        }
        asm volatile("s_waitcnt vmcnt(0)" ::: "memory");
        __syncthreads();

        // ---- compute this K-phase: 9 taps x NM x 2 MFMA per wave ----
        #pragma unroll
        for (int dy = 0; dy < 3; ++dy)
            #pragma unroll
            for (int dx = 0; dx < 3; ++dx) {
                const int t = dy * 3 + dx;
                short8 bfr[2];
                #pragma unroll
                for (int nf = 0; nf < 2; ++nf) {
                    int pp2 = (wv + dy) * 34 + nf * 16 + lo + dx;
                    bfr[nf] = *(const short8*)&lds[pp2 * 32 + ((slr ^ ((pp2 >> 1) & 3)) << 3)];
                }
                short8 afr[NM];
                #pragma unroll
                for (int mf = 0; mf < NM; ++mf)
                    afr[mf] = *(const short8*)&wB[((t * OC + mf * 16 + lo) * 64) + h * 32 + g8];
                #pragma unroll
                for (int mf = 0; mf < NM; ++mf)
                    #pragma unroll
                    for (int nf = 0; nf < 2; ++nf)
                        acc[mf][nf] = __builtin_amdgcn_mfma_f32_16x16x32_bf16(
                            afr[mf], bfr[nf], acc[mf][nf], 0, 0, 0);
            }
    }

    // ---- epilogue: C col=lane&15 (pixel), row=(lane>>4)*4+j (outch); NHWC 8B stores ----
    #pragma unroll
    for (int nf = 0; nf < 2; ++nf) {
        int r = h0 + wv;
        int x = w0 + nf * 16 + lo;
        int pos = r * Ww + x;
        float wmv = wm[pos];
        #pragma unroll
        for (int mf = 0; mf < NM; ++mf) {
            int o0 = ocb + mf * 16 + slr * 4;
            size_t oi = (size_t)pos * 64 + o0;
            float v[4];
            #pragma unroll
            for (int j = 0; j < 4; ++j) v[j] = acc[mf][nf][j] * wmv;
            if (MODE == 0) {
                #pragma unroll
                for (int j = 0; j < 4; ++j) v[j] = fmaxf(v[j], 0.f);
            } else if (MODE == 1) {
                short4v bv = *(const short4v*)&baseb[oi];
                #pragma unroll
                for (int j = 0; j < 4; ++j) v[j] += bf2f((ushort_t)bv[j]);
            }
            short4v sv;
            #pragma unroll
            for (int j = 0; j < 4; ++j) sv[j] = (short)f2bf(v[j]);
            *(short4v*)&outb[oi] = sv;
        }
    }
}

// ---------------- gather + MLP via MFMA: 64 pts/block, 16 pts/wave --------------------
__global__ __launch_bounds__(256) void k_gather_mlp(
    const ushort_t* __restrict__ F, const ushort_t* __restrict__ G,
    const int* __restrict__ yi, const float* __restrict__ m,
    const ushort_t* __restrict__ wA1, const ushort_t* __restrict__ wA2,
    const ushort_t* __restrict__ wA3, float* __restrict__ pvd) {
    __shared__ __align__(16) ushort_t HA[4 * 16 * PADH];
    __shared__ __align__(16) ushort_t HB[4 * 16 * PADH];
    const int tid = threadIdx.x, wv = tid >> 6, ln = tid & 63;
    ushort_t* ha = HA + wv * 16 * PADH;
    ushort_t* hb = HB + wv * 16 * PADH;
    const int t0 = blockIdx.x * 64 + wv * 16;
    const int b = t0 >> 15;
    const int lo = ln & 15, g8 = (ln >> 4) * 8;

    #pragma unroll
    for (int rnd = 0; rnd < 2; ++rnd) {
        int j = rnd * 64 + ln;
        if (j < 96) {
            int pt = j / 6, sl = j - pt * 6;
            int n = (t0 + pt) & (Nn - 1);
            int pos = yi[n];
            size_t gi = ((size_t)(b * HW) + pos) * 64 + sl * 8;
            short8 fa = *(const short8*)&F[gi];
            short8 ga = *(const short8*)&G[gi];
            short8 sv;
            #pragma unroll
            for (int i = 0; i < 8; ++i)
                sv[i] = (short)f2bf(bf2f((ushort_t)fa[i]) + bf2f((ushort_t)ga[i]));
            *(short8*)&ha[pt * PADH + sl * 8] = sv;
        }
    }
    if (ln < 16) {
        int pt = ln;
        int n = (t0 + pt) & (Nn - 1);
        int pos = yi[n];
        float det = m[0] * (m[4] * m[8] - m[5] * m[7])
                  - m[1] * (m[3] * m[8] - m[5] * m[6])
                  + m[2] * (m[3] * m[7] - m[4] * m[6]);
        int yr = pos >> 8, xc = pos & 255;
        float wc = m[6] * (float)xc + m[7] * (float)yr + m[8];
        float cw = fmaxf(fabsf(wc), 1e-8f);
        float dsda = fabsf(det) / (cw * cw * cw);
        float ld = logf(dsda + 1e-8f);
        const ushort_t one = f2bf(1.0f);
        short8 z = {0, 0, 0, 0, 0, 0, 0, 0};
        short8 sa = z; sa[0] = (short)f2bf(ld); sa[1] = (short)one;
        short8 sb = z; sb[0] = (short)one;
        *(short8*)&ha[pt * PADH + 48] = sa;
        *(short8*)&ha[pt * PADH + 56] = z;
        *(short8*)&hb[pt * PADH + 48] = sb;
        *(short8*)&hb[pt * PADH + 56] = z;
    }
    asm volatile("s_waitcnt lgkmcnt(0)" ::: "memory");

    f32x4 a1[3] = {{0.f,0.f,0.f,0.f},{0.f,0.f,0.f,0.f},{0.f,0.f,0.f,0.f}};
    #pragma unroll
    for (int ks = 0; ks < 2; ++ks) {
        short8 bf = *(const short8*)&ha[lo * PADH + ks * 32 + g8];
        #pragma unroll
        for (int mf = 0; mf < 3; ++mf) {
            short8 af = *(const short8*)&wA1[(mf * 16 + lo) * 64 + ks * 32 + g8];
            a1[mf] = __builtin_amdgcn_mfma_f32_16x16x32_bf16(af, bf, a1[mf], 0, 0, 0);
        }
    }
    #pragma unroll
    for (int mf = 0; mf < 3; ++mf) {
        short4v sv;
        #pragma unroll
        for (int j = 0; j < 4; ++j) sv[j] = (short)f2bf(fmaxf(a1[mf][j], 0.f));
        *(short4v*)&hb[lo * PADH + mf * 16 + (ln >> 4) * 4] = sv;
    }
    asm volatile("s_waitcnt lgkmcnt(0)" ::: "memory");

    f32x4 a2[3] = {{0.f,0.f,0.f,0.f},{0.f,0.f,0.f,0.f},{0.f,0.f,0.f,0.f}};
    #pragma unroll
    for (int ks = 0; ks < 2; ++ks) {
        short8 bf = *(const short8*)&hb[lo * PADH + ks * 32 + g8];
        #pragma unroll
        for (int mf = 0; mf < 3; ++mf) {
            short8 af = *(const short8*)&wA2[(mf * 16 + lo) * 64 + ks * 32 + g8];
            a2[mf] = __builtin_amdgcn_mfma_f32_16x16x32_bf16(af, bf, a2[mf], 0, 0, 0);
        }
    }
    #pragma unroll
    for (int mf = 0; mf < 3; ++mf) {
        short4v sv;
        #pragma unroll
        for (int j = 0; j < 4; ++j) sv[j] = (short)f2bf(fmaxf(a2[mf][j], 0.f));
        *(short4v*)&ha[lo * PADH + mf * 16 + (ln >> 4) * 4] = sv;
    }
    asm volatile("s_waitcnt lgkmcnt(0)" ::: "memory");

    f32x4 a3 = {0.f, 0.f, 0.f, 0.f};
    #pragma unroll
    for (int ks = 0; ks < 2; ++ks) {
        short8 bf = *(const short8*)&ha[lo * PADH + ks * 32 + g8];
        short8 af = *(const short8*)&wA3[lo * 64 + ks * 32 + g8];
        a3 = __builtin_amdgcn_mfma_f32_16x16x32_bf16(af, bf, a3, 0, 0, 0);
    }
    if (ln < 16) {
        int n = (t0 + lo) & (Nn - 1);
        int pos = yi[n];
        #pragma unroll
        for (int j = 0; j < 3; ++j)
            pvd[(size_t)(b * Pp + j) * HW + pos] = a3[j];
    }
}

// ---------------- out[b,c,pos] = sum_p pvd[b,p,pos] * xs[p,b,c,pos] ----------------
__global__ __launch_bounds__(256) void k_blend(const float4* __restrict__ xs,
                                               const float4* __restrict__ pvd,
                                               float4* __restrict__ out) {
    int i = blockIdx.x * 256 + threadIdx.x;   // over B*C*HW/4
    int pos4 = i & (HW / 4 - 1);
    int bc = i >> 14;
    int b = bc >> 6;
    float4 acc = make_float4(0.f, 0.f, 0.f, 0.f);
    #pragma unroll
    for (int p = 0; p < Pp; ++p) {
        float4 pv = pvd[(b * Pp + p) * (HW / 4) + pos4];
        float4 x = xs[p * (Bb * Cc * HW / 4) + i];
        acc.x += pv.x * x.x;
        acc.y += pv.y * x.y;
        acc.z += pv.z * x.z;
        acc.w += pv.w * x.w;
    }
    out[i] = acc;
}

extern "C" void kernel_launch(void* const* d_in, const int* in_sizes, int n_in,
                              void* d_out, int out_size, void* d_ws, size_t ws_size,
                              hipStream_t stream) {
    const float* xs        = (const float*)d_in[0];
    const float* mask      = (const float*)d_in[1];
    const int*   yi        = (const int*)d_in[2];
    const float* m         = (const float*)d_in[3];
    const float* ss_res_w  = (const float*)d_in[4];
    const float* ss_out_w  = (const float*)d_in[5];
    const float* feat_res_w= (const float*)d_in[6];
    const float* w1 = (const float*)d_in[7];
    const float* b1 = (const float*)d_in[8];
    const float* w2 = (const float*)d_in[9];
    const float* b2 = (const float*)d_in[10];
    const float* w3 = (const float*)d_in[11];
    const float* b3 = (const float*)d_in[12];

    // ws: wm f32 | zpage (64 f32) | pvd f32 | wB | wA | X (P,B,HW,64) | U | V | F | G
    float* wm    = (float*)d_ws;
    float* zpage = wm + HW;
    float* pvd   = zpage + 64;
    ushort_t* wB = (ushort_t*)(pvd + (size_t)Bb * Pp * HW);
    constexpr size_t RES_T = 12 * 9 * 64 * 64;     // 442368
    constexpr size_t OUT_T = 3 * 9 * 16 * 64;      // 27648
    constexpr size_t TRK_T = 4 * 9 * 48 * 64;      // 110592
    constexpr size_t MLP_T = 7168;
    constexpr size_t ZT = (size_t)Pp * Bb * HW * 64;   // 25165824
    ushort_t* wA = wB + RES_T + OUT_T + TRK_T;
    ushort_t* X = wA + MLP_T;
    ushort_t* U = X + ZT;
    ushort_t* V = U + ZT;
    ushort_t* F = V + ZT;
    ushort_t* G = F + (size_t)Bb * HW * 64;
    const ushort_t* zp = (const ushort_t*)zpage;

    k_wm<<<HW / 256, 256, 0, stream>>>(mask, wm, zpage);
    k_wx_res  <<<RES_T / 256, 256, 0, stream>>>(ss_res_w, wB);
    k_wx_out  <<<OUT_T / 256, 256, 0, stream>>>(ss_out_w, wB + RES_T);
    k_wx_trunk<<<TRK_T / 256, 256, 0, stream>>>(feat_res_w, wB + RES_T + OUT_T);
    k_wx_mlp  <<<MLP_T / 256, 256, 0, stream>>>(w1, b1, w2, b2, w3, b3, wA);

    const dim3 gridP(Ww / TW, Hh / TH, Pp * Bb);   // (8, 64, 6)
    const dim3 gridT(Ww / TW, Hh / TH, Bb);        // (8, 64, 2)
    const int RS = 4 * 9 * 64 * 64;                // per-pyramid res weight stride
    const int OS = 9 * 16 * 64;                    // per-pyramid out weight stride

    k_xm<<<dim3(HW / 64, Pp * Bb), 256, 0, stream>>>(xs, mask, X);
    k_mconv<64, 0, false><<<gridP, 256, 0, stream>>>(X, wB,             RS, wm, zp, nullptr, U);
    k_mconv<64, 1, false><<<gridP, 256, 0, stream>>>(U, wB + 1 * 36864, RS, wm, zp, X,       V);
    k_mconv<64, 0, false><<<gridP, 256, 0, stream>>>(V, wB + 2 * 36864, RS, wm, zp, nullptr, U);
    k_mconv<64, 1, false><<<gridP, 256, 0, stream>>>(U, wB + 3 * 36864, RS, wm, zp, V,       V);
    k_mconv<16, 2, true ><<<gridP, 256, 0, stream>>>(V, wB + RES_T,     OS, wm, zp, nullptr, F);

    const ushort_t* tw = wB + RES_T + OUT_T;
    k_mconv<48, 0, false><<<gridT, 256, 0, stream>>>(F, tw,             0, wm, zp, nullptr, U);
    k_mconv<48, 1, false><<<gridT, 256, 0, stream>>>(U, tw + 1 * 27648, 0, wm, zp, F,       G);
    k_mconv<48, 0, false><<<gridT, 256, 0, stream>>>(G, tw + 2 * 27648, 0, wm, zp, nullptr, U);
    k_mconv<48, 1, false><<<gridT, 256, 0, stream>>>(U, tw + 3 * 27648, 0, wm, zp, G,       G);

    k_zero<<<(Bb * Pp * HW / 4) / 256, 256, 0, stream>>>((float4*)pvd);
    k_gather_mlp<<<Bb * Nn / 64, 256, 0, stream>>>(F, G, yi, m,
        wA, wA + 3072, wA + 6144, pvd);
    k_blend<<<(Bb * Cc * HW / 4) / 256, 256, 0, stream>>>((const float4*)xs, (const float4*)pvd,
                                                          (float4*)d_out);
}

// Round 8
// 329.820 us; speedup vs baseline: 2.1391x; 2.1391x over previous
//
#include <hip/hip_runtime.h>
#include <hip/hip_bf16.h>

typedef unsigned short ushort_t;
typedef __attribute__((ext_vector_type(8))) short short8;
typedef __attribute__((ext_vector_type(4))) short short4v;
typedef __attribute__((ext_vector_type(4))) float f32x4;

// Problem constants
constexpr int Hh = 256, Ww = 256, HW = Hh * Ww;
constexpr int Bb = 2, Cc = 64, Pp = 3, NOo = 16, FEXc = 48, Nn = 32768;
constexpr int TW = 32, TH = 4;       // conv spatial tile per block
constexpr int HALOP = (TH + 2) * 34; // 204 halo pixels
constexpr int AROWS = 208;           // staged act rows (26 DMA x 8 rows)
constexpr int PADH = 72;             // gather-MLP LDS point stride (bf16)

__device__ inline ushort_t f2bf(float v) {
    __hip_bfloat16 h = __float2bfloat16(v);
    return *(ushort_t*)&h;
}
__device__ inline float bf2f(ushort_t u) {
    __hip_bfloat16 h = *(__hip_bfloat16*)&u;
    return __bfloat162float(h);
}
// async 16B global->LDS DMA: dest = lds base (wave-uniform) + lane*16
__device__ inline void gload_lds16(const ushort_t* g, ushort_t* l) {
    __builtin_amdgcn_global_load_lds(
        (const __attribute__((address_space(1))) unsigned int*)g,
        (__attribute__((address_space(3))) unsigned int*)l, 16, 0, 0);
}

// -------- mask weight: wm = mask / max(avg3x3(mask), 1e-8); also zero the zpage ------
__global__ __launch_bounds__(256) void k_wm(const float* __restrict__ mask,
                                            float* __restrict__ wm,
                                            float* __restrict__ zpage) {
    int pos = blockIdx.x * 256 + threadIdx.x;
    if (blockIdx.x == 0 && threadIdx.x < 64) zpage[threadIdx.x] = 0.f;  // 256B zeros
    int h = pos >> 8, w = pos & 255;
    float s = 0.f;
    #pragma unroll
    for (int dy = -1; dy <= 1; ++dy)
        #pragma unroll
        for (int dx = -1; dx <= 1; ++dx) {
            int hh = h + dy, ww = w + dx;
            if (hh >= 0 && hh < Hh && ww >= 0 && ww < Ww) s += mask[hh * Ww + ww];
        }
    float avg = s * (1.f / 9.f);
    wm[pos] = mask[pos] / fmaxf(avg, 1e-8f);
}

// ---------------- zero a float4 buffer ----------------
__global__ __launch_bounds__(256) void k_zero(float4* __restrict__ p) {
    p[blockIdx.x * 256 + threadIdx.x] = make_float4(0.f, 0.f, 0.f, 0.f);
}

// ---------------- weight transforms: fp32 [oc][cin][3][3] -> bf16 [tap][oc][c64] ----
__global__ __launch_bounds__(256) void k_wx_res(const float* __restrict__ src,
                                                ushort_t* __restrict__ dst) {
    int idx = blockIdx.x * 256 + threadIdx.x;          // < 12*9*64*64 = 442368
    int j = idx / 36864; int rem = idx - j * 36864;
    int t = rem >> 12; int o = (rem >> 6) & 63; int c = rem & 63;
    dst[idx] = f2bf(src[j * 36864 + o * 576 + c * 9 + t]);
}
__global__ __launch_bounds__(256) void k_wx_out(const float* __restrict__ src,
                                                ushort_t* __restrict__ dst) {
    int idx = blockIdx.x * 256 + threadIdx.x;          // < 3*9*16*64 = 27648
    int i = idx / 9216; int rem = idx - i * 9216;
    int t = rem >> 10; int o = (rem >> 6) & 15; int c = rem & 63;
    dst[idx] = f2bf(src[i * 9216 + o * 576 + c * 9 + t]);
}
__global__ __launch_bounds__(256) void k_wx_trunk(const float* __restrict__ src,
                                                  ushort_t* __restrict__ dst) {
    int idx = blockIdx.x * 256 + threadIdx.x;          // < 4*9*48*64 = 110592
    int j = idx / 27648; int rem = idx - j * 27648;
    int t = rem / 3072; int rem2 = rem - t * 3072;
    int o = rem2 >> 6; int c = rem2 & 63;
    float v = (c < 48) ? src[j * (48 * 48 * 9) + o * 432 + c * 9 + t] : 0.f;
    dst[idx] = f2bf(v);
}
// MLP weights -> A-frag layout [out][k64] bf16, biases folded at k=49 (L1) / 48 (L2) / 49 (L3)
__global__ __launch_bounds__(256) void k_wx_mlp(
    const float* __restrict__ w1, const float* __restrict__ b1,
    const float* __restrict__ w2, const float* __restrict__ b2,
    const float* __restrict__ w3, const float* __restrict__ b3,
    ushort_t* __restrict__ dst) {
    int idx = blockIdx.x * 256 + threadIdx.x;          // < 7168
    float v = 0.f;
    if (idx < 3072) {                                  // wA1 [48][64]
        int o = idx >> 6, c = idx & 63;
        v = (c < 49) ? w1[o * 49 + c] : (c == 49 ? b1[o] : 0.f);
    } else if (idx < 6144) {                           // wA2 [48][64]
        int o = (idx - 3072) >> 6, c = idx & 63;
        v = (c < 48) ? w2[o * 48 + c] : (c == 48 ? b2[o] : 0.f);
    } else {                                           // wA3 [16][64]
        int o = (idx - 6144) >> 6, c = idx & 63;
        if (o < 3) v = (c < 48) ? w3[o * 48 + c] : (c == 49 ? b3[o] : 0.f);
    }
    dst[idx] = f2bf(v);
}

// ------- xs: NCHW fp32 -> masked NHWC bf16, all pyramids (z = i*B + b) --------------
__global__ __launch_bounds__(256) void k_xm(const float* __restrict__ xs,
                                            const float* __restrict__ mask,
                                            ushort_t* __restrict__ X) {
    __shared__ float l[64 * 65];
    const int p0 = blockIdx.x * 64;
    const size_t zoff = (size_t)blockIdx.y * 64 * HW;
    const int tid = threadIdx.x;
    const int px = tid & 63;
    const float mv = mask[p0 + px];
    #pragma unroll
    for (int k = 0; k < 16; ++k) {
        int c = (tid >> 6) + 4 * k;
        l[c * 65 + px] = xs[zoff + (size_t)c * HW + p0 + px] * mv;
    }
    __syncthreads();
    #pragma unroll
    for (int k = 0; k < 2; ++k) {
        int idx = tid + k * 256;
        int p = idx >> 3, c8 = idx & 7;
        short8 v;
        #pragma unroll
        for (int i = 0; i < 8; ++i) v[i] = (short)f2bf(l[(c8 * 8 + i) * 65 + p]);
        *(short8*)&X[zoff + (size_t)(p0 + p) * 64 + c8 * 8] = v;
    }
}

// ---------------- MFMA implicit-GEMM 3x3 conv (NHWC bf16, ch stride 64) ------------
// BOTH operands staged in LDS. Act: TH=4 halo (208 rows x 128B), staged ONCE,
// 8-slot XOR swizzle (slot d holds global chunk d^(pp&7)). Weights: per 32-ch K-phase
// (9*OC rows x 64B), restaged between phases (L2-resident), 4-slot XOR swizzle
// p = j ^ ((r^(r>>2))&3). OOB act lanes DMA from zero page (per-lane global source).
// z = pyramid*2 + batch (trunk: z=batch, wstride=0). TOF: out -> F at chan (z>>1)*16.
// MODE 0: out = relu(conv*wm)    MODE 1: out = base + conv*wm    MODE 2: out = conv*wm
template <int OC, int MODE, bool TOF>
__global__ __launch_bounds__(256) void k_mconv(
    const ushort_t* __restrict__ in,
    const ushort_t* __restrict__ wgt, int wstride,
    const float* __restrict__ wm,
    const ushort_t* __restrict__ zp,      // >=256B of zeros, 16B aligned
    const ushort_t* __restrict__ base,
    ushort_t* __restrict__ out) {
    constexpr int NM = OC / 16;
    constexpr int WROWS = 9 * OC;         // weight rows per phase (32 ch = 64B each)
    constexpr int WDMA = WROWS / 16;      // 1KB DMA instructions per phase
    __shared__ __align__(1024) ushort_t alds[AROWS * 64];
    __shared__ __align__(1024) ushort_t wlds[WROWS * 32];
    const int tid = threadIdx.x;
    const int wv = tid >> 6;
    const int ln = tid & 63;
    const int w0 = blockIdx.x * TW, h0 = blockIdx.y * TH;
    const int zz = blockIdx.z;
    const ushort_t* inb = in + (size_t)zz * HW * 64;
    const ushort_t* wB = wgt + (size_t)(zz >> 1) * wstride;
    const ushort_t* baseb = base ? base + (size_t)zz * HW * 64 : nullptr;
    ushort_t* outb = TOF ? out + (size_t)(zz & 1) * HW * 64 : out + (size_t)zz * HW * 64;
    const int ocb = TOF ? (zz >> 1) * 16 : 0;

    const int lo = ln & 15, slr = ln >> 4, g8 = slr * 8;

    f32x4 acc[NM][2];
    #pragma unroll
    for (int mf = 0; mf < NM; ++mf)
        #pragma unroll
        for (int nf = 0; nf < 2; ++nf) acc[mf][nf] = (f32x4){0.f, 0.f, 0.f, 0.f};

    // ---- stage activations once: 26 DMA (8 rows x 128B each) ----
    #pragma unroll
    for (int k = 0; k < 7; ++k) {
        int s = wv + 4 * k;
        if (s < 26) {
            int pp = s * 8 + (ln >> 3);            // 0..207
            int r = (pp * 241) >> 13;              // pp/34
            int col = pp - r * 34;
            int gh = h0 + r - 1, gw = w0 + col - 1;
            bool ok = (pp < HALOP) & (gh >= 0) & (gh < Hh) & (gw >= 0) & (gw < Ww);
            int che = ((ln & 7) ^ (pp & 7)) << 3;  // element offset of 16B chunk
            const ushort_t* src = ok ? inb + (size_t)(gh * Ww + gw) * 64 + che : zp + che;
            gload_lds16(src, &alds[s * 512]);
        }
    }

    #pragma unroll
    for (int h = 0; h < 2; ++h) {
        if (h) __syncthreads();            // all waves done reading wlds phase 0
        // ---- stage weights for this 32-ch K-phase ----
        #pragma unroll
        for (int k = 0; k < (WDMA + 3) / 4; ++k) {
            int s = wv + 4 * k;
            if (s < WDMA) {
                int r = s * 16 + (ln >> 2);        // weight row (tap*OC + oc)
                int d = ln & 3;
                int j = d ^ ((r ^ (r >> 2)) & 3);  // global 16B chunk for this slot
                gload_lds16(wB + (size_t)r * 64 + h * 32 + j * 8, &wlds[s * 512]);
            }
        }
        asm volatile("s_waitcnt vmcnt(0)" ::: "memory");
        __syncthreads();

        // ---- compute this K-phase: 9 taps x NM x 2 MFMA per wave ----
        #pragma unroll
        for (int dy = 0; dy < 3; ++dy)
            #pragma unroll
            for (int dx = 0; dx < 3; ++dx) {
                const int t = dy * 3 + dx;
                short8 bfr[2];
                #pragma unroll
                for (int nf = 0; nf < 2; ++nf) {
                    int pp2 = (wv + dy) * 34 + nf * 16 + lo + dx;
                    bfr[nf] = *(const short8*)
                        &alds[pp2 * 64 + (((h * 4 + slr) ^ (pp2 & 7)) << 3)];
                }
                short8 afr[NM];
                #pragma unroll
                for (int mf = 0; mf < NM; ++mf) {
                    int r = t * OC + mf * 16 + lo;
                    afr[mf] = *(const short8*)
                        &wlds[r * 32 + ((slr ^ ((r ^ (r >> 2)) & 3)) << 3)];
                }
                #pragma unroll
                for (int mf = 0; mf < NM; ++mf)
                    #pragma unroll
                    for (int nf = 0; nf < 2; ++nf)
                        acc[mf][nf] = __builtin_amdgcn_mfma_f32_16x16x32_bf16(
                            afr[mf], bfr[nf], acc[mf][nf], 0, 0, 0);
            }
    }

    // ---- epilogue: C col=lane&15 (pixel), row=(lane>>4)*4+j (outch); NHWC 8B stores ----
    #pragma unroll
    for (int nf = 0; nf < 2; ++nf) {
        int r = h0 + wv;
        int x = w0 + nf * 16 + lo;
        int pos = r * Ww + x;
        float wmv = wm[pos];
        #pragma unroll
        for (int mf = 0; mf < NM; ++mf) {
            int o0 = ocb + mf * 16 + slr * 4;
            size_t oi = (size_t)pos * 64 + o0;
            float v[4];
            #pragma unroll
            for (int j = 0; j < 4; ++j) v[j] = acc[mf][nf][j] * wmv;
            if (MODE == 0) {
                #pragma unroll
                for (int j = 0; j < 4; ++j) v[j] = fmaxf(v[j], 0.f);
            } else if (MODE == 1) {
                short4v bv = *(const short4v*)&baseb[oi];
                #pragma unroll
                for (int j = 0; j < 4; ++j) v[j] += bf2f((ushort_t)bv[j]);
            }
            short4v sv;
            #pragma unroll
            for (int j = 0; j < 4; ++j) sv[j] = (short)f2bf(v[j]);
            *(short4v*)&outb[oi] = sv;
        }
    }
}

// ---------------- gather + MLP via MFMA: 64 pts/block, 16 pts/wave --------------------
__global__ __launch_bounds__(256) void k_gather_mlp(
    const ushort_t* __restrict__ F, const ushort_t* __restrict__ G,
    const int* __restrict__ yi, const float* __restrict__ m,
    const ushort_t* __restrict__ wA1, const ushort_t* __restrict__ wA2,
    const ushort_t* __restrict__ wA3, float* __restrict__ pvd) {
    __shared__ __align__(16) ushort_t HA[4 * 16 * PADH];
    __shared__ __align__(16) ushort_t HB[4 * 16 * PADH];
    const int tid = threadIdx.x, wv = tid >> 6, ln = tid & 63;
    ushort_t* ha = HA + wv * 16 * PADH;
    ushort_t* hb = HB + wv * 16 * PADH;
    const int t0 = blockIdx.x * 64 + wv * 16;
    const int b = t0 >> 15;
    const int lo = ln & 15, g8 = (ln >> 4) * 8;

    #pragma unroll
    for (int rnd = 0; rnd < 2; ++rnd) {
        int j = rnd * 64 + ln;
        if (j < 96) {
            int pt = j / 6, sl = j - pt * 6;
            int n = (t0 + pt) & (Nn - 1);
            int pos = yi[n];
            size_t gi = ((size_t)(b * HW) + pos) * 64 + sl * 8;
            short8 fa = *(const short8*)&F[gi];
            short8 ga = *(const short8*)&G[gi];
            short8 sv;
            #pragma unroll
            for (int i = 0; i < 8; ++i)
                sv[i] = (short)f2bf(bf2f((ushort_t)fa[i]) + bf2f((ushort_t)ga[i]));
            *(short8*)&ha[pt * PADH + sl * 8] = sv;
        }
    }
    if (ln < 16) {
        int pt = ln;
        int n = (t0 + pt) & (Nn - 1);
        int pos = yi[n];
        float det = m[0] * (m[4] * m[8] - m[5] * m[7])
                  - m[1] * (m[3] * m[8] - m[5] * m[6])
                  + m[2] * (m[3] * m[7] - m[4] * m[6]);
        int yr = pos >> 8, xc = pos & 255;
        float wc = m[6] * (float)xc + m[7] * (float)yr + m[8];
        float cw = fmaxf(fabsf(wc), 1e-8f);
        float dsda = fabsf(det) / (cw * cw * cw);
        float ld = logf(dsda + 1e-8f);
        const ushort_t one = f2bf(1.0f);
        short8 z = {0, 0, 0, 0, 0, 0, 0, 0};
        short8 sa = z; sa[0] = (short)f2bf(ld); sa[1] = (short)one;
        short8 sb = z; sb[0] = (short)one;
        *(short8*)&ha[pt * PADH + 48] = sa;
        *(short8*)&ha[pt * PADH + 56] = z;
        *(short8*)&hb[pt * PADH + 48] = sb;
        *(short8*)&hb[pt * PADH + 56] = z;
    }
    asm volatile("s_waitcnt lgkmcnt(0)" ::: "memory");

    f32x4 a1[3] = {{0.f,0.f,0.f,0.f},{0.f,0.f,0.f,0.f},{0.f,0.f,0.f,0.f}};
    #pragma unroll
    for (int ks = 0; ks < 2; ++ks) {
        short8 bf = *(const short8*)&ha[lo * PADH + ks * 32 + g8];
        #pragma unroll
        for (int mf = 0; mf < 3; ++mf) {
            short8 af = *(const short8*)&wA1[(mf * 16 + lo) * 64 + ks * 32 + g8];
            a1[mf] = __builtin_amdgcn_mfma_f32_16x16x32_bf16(af, bf, a1[mf], 0, 0, 0);
        }
    }
    #pragma unroll
    for (int mf = 0; mf < 3; ++mf) {
        short4v sv;
        #pragma unroll
        for (int j = 0; j < 4; ++j) sv[j] = (short)f2bf(fmaxf(a1[mf][j], 0.f));
        *(short4v*)&hb[lo * PADH + mf * 16 + (ln >> 4) * 4] = sv;
    }
    asm volatile("s_waitcnt lgkmcnt(0)" ::: "memory");

    f32x4 a2[3] = {{0.f,0.f,0.f,0.f},{0.f,0.f,0.f,0.f},{0.f,0.f,0.f,0.f}};
    #pragma unroll
    for (int ks = 0; ks < 2; ++ks) {
        short8 bf = *(const short8*)&hb[lo * PADH + ks * 32 + g8];
        #pragma unroll
        for (int mf = 0; mf < 3; ++mf) {
            short8 af = *(const short8*)&wA2[(mf * 16 + lo) * 64 + ks * 32 + g8];
            a2[mf] = __builtin_amdgcn_mfma_f32_16x16x32_bf16(af, bf, a2[mf], 0, 0, 0);
        }
    }
    #pragma unroll
    for (int mf = 0; mf < 3; ++mf) {
        short4v sv;
        #pragma unroll
        for (int j = 0; j < 4; ++j) sv[j] = (short)f2bf(fmaxf(a2[mf][j], 0.f));
        *(short4v*)&ha[lo * PADH + mf * 16 + (ln >> 4) * 4] = sv;
    }
    asm volatile("s_waitcnt lgkmcnt(0)" ::: "memory");

    f32x4 a3 = {0.f, 0.f, 0.f, 0.f};
    #pragma unroll
    for (int ks = 0; ks < 2; ++ks) {
        short8 bf = *(const short8*)&ha[lo * PADH + ks * 32 + g8];
        short8 af = *(const short8*)&wA3[lo * 64 + ks * 32 + g8];
        a3 = __builtin_amdgcn_mfma_f32_16x16x32_bf16(af, bf, a3, 0, 0, 0);
    }
    if (ln < 16) {
        int n = (t0 + lo) & (Nn - 1);
        int pos = yi[n];
        #pragma unroll
        for (int j = 0; j < 3; ++j)
            pvd[(size_t)(b * Pp + j) * HW + pos] = a3[j];
    }
}

// ---------------- out[b,c,pos] = sum_p pvd[b,p,pos] * xs[p,b,c,pos] ----------------
__global__ __launch_bounds__(256) void k_blend(const float4* __restrict__ xs,
                                               const float4* __restrict__ pvd,
                                               float4* __restrict__ out) {
    int i = blockIdx.x * 256 + threadIdx.x;   // over B*C*HW/4
    int pos4 = i & (HW / 4 - 1);
    int bc = i >> 14;
    int b = bc >> 6;
    float4 acc = make_float4(0.f, 0.f, 0.f, 0.f);
    #pragma unroll
    for (int p = 0; p < Pp; ++p) {
        float4 pv = pvd[(b * Pp + p) * (HW / 4) + pos4];
        float4 x = xs[p * (Bb * Cc * HW / 4) + i];
        acc.x += pv.x * x.x;
        acc.y += pv.y * x.y;
        acc.z += pv.z * x.z;
        acc.w += pv.w * x.w;
    }
    out[i] = acc;
}

extern "C" void kernel_launch(void* const* d_in, const int* in_sizes, int n_in,
                              void* d_out, int out_size, void* d_ws, size_t ws_size,
                              hipStream_t stream) {
    const float* xs        = (const float*)d_in[0];
    const float* mask      = (const float*)d_in[1];
    const int*   yi        = (const int*)d_in[2];
    const float* m         = (const float*)d_in[3];
    const float* ss_res_w  = (const float*)d_in[4];
    const float* ss_out_w  = (const float*)d_in[5];
    const float* feat_res_w= (const float*)d_in[6];
    const float* w1 = (const float*)d_in[7];
    const float* b1 = (const float*)d_in[8];
    const float* w2 = (const float*)d_in[9];
    const float* b2 = (const float*)d_in[10];
    const float* w3 = (const float*)d_in[11];
    const float* b3 = (const float*)d_in[12];

    // ws: wm f32 | zpage (64 f32) | pvd f32 | wB | wA | X (P,B,HW,64) | U | V | F | G
    float* wm    = (float*)d_ws;
    float* zpage = wm + HW;
    float* pvd   = zpage + 64;
    ushort_t* wB = (ushort_t*)(pvd + (size_t)Bb * Pp * HW);
    constexpr size_t RES_T = 12 * 9 * 64 * 64;     // 442368
    constexpr size_t OUT_T = 3 * 9 * 16 * 64;      // 27648
    constexpr size_t TRK_T = 4 * 9 * 48 * 64;      // 110592
    constexpr size_t MLP_T = 7168;
    constexpr size_t ZT = (size_t)Pp * Bb * HW * 64;   // 25165824
    ushort_t* wA = wB + RES_T + OUT_T + TRK_T;
    ushort_t* X = wA + MLP_T;
    ushort_t* U = X + ZT;
    ushort_t* V = U + ZT;
    ushort_t* F = V + ZT;
    ushort_t* G = F + (size_t)Bb * HW * 64;
    const ushort_t* zp = (const ushort_t*)zpage;

    k_wm<<<HW / 256, 256, 0, stream>>>(mask, wm, zpage);
    k_wx_res  <<<RES_T / 256, 256, 0, stream>>>(ss_res_w, wB);
    k_wx_out  <<<OUT_T / 256, 256, 0, stream>>>(ss_out_w, wB + RES_T);
    k_wx_trunk<<<TRK_T / 256, 256, 0, stream>>>(feat_res_w, wB + RES_T + OUT_T);
    k_wx_mlp  <<<MLP_T / 256, 256, 0, stream>>>(w1, b1, w2, b2, w3, b3, wA);

    const dim3 gridP(Ww / TW, Hh / TH, Pp * Bb);   // (8, 64, 6)
    const dim3 gridT(Ww / TW, Hh / TH, Bb);        // (8, 64, 2)
    const int RS = 4 * 9 * 64 * 64;                // per-pyramid res weight stride
    const int OS = 9 * 16 * 64;                    // per-pyramid out weight stride

    k_xm<<<dim3(HW / 64, Pp * Bb), 256, 0, stream>>>(xs, mask, X);
    k_mconv<64, 0, false><<<gridP, 256, 0, stream>>>(X, wB,             RS, wm, zp, nullptr, U);
    k_mconv<64, 1, false><<<gridP, 256, 0, stream>>>(U, wB + 1 * 36864, RS, wm, zp, X,       V);
    k_mconv<64, 0, false><<<gridP, 256, 0, stream>>>(V, wB + 2 * 36864, RS, wm, zp, nullptr, U);
    k_mconv<64, 1, false><<<gridP, 256, 0, stream>>>(U, wB + 3 * 36864, RS, wm, zp, V,       V);
    k_mconv<16, 2, true ><<<gridP, 256, 0, stream>>>(V, wB + RES_T,     OS, wm, zp, nullptr, F);

    const ushort_t* tw = wB + RES_T + OUT_T;
    k_mconv<48, 0, false><<<gridT, 256, 0, stream>>>(F, tw,             0, wm, zp, nullptr, U);
    k_mconv<48, 1, false><<<gridT, 256, 0, stream>>>(U, tw + 1 * 27648, 0, wm, zp, F,       G);
    k_mconv<48, 0, false><<<gridT, 256, 0, stream>>>(G, tw + 2 * 27648, 0, wm, zp, nullptr, U);
    k_mconv<48, 1, false><<<gridT, 256, 0, stream>>>(U, tw + 3 * 27648, 0, wm, zp, G,       G);

    k_zero<<<(Bb * Pp * HW / 4) / 256, 256, 0, stream>>>((float4*)pvd);
    k_gather_mlp<<<Bb * Nn / 64, 256, 0, stream>>>(F, G, yi, m,
        wA, wA + 3072, wA + 6144, pvd);
    k_blend<<<(Bb * Cc * HW / 4) / 256, 256, 0, stream>>>((const float4*)xs, (const float4*)pvd,
                                                          (float4*)d_out);
}

// Round 9
// 324.532 us; speedup vs baseline: 2.1740x; 1.0163x over previous
//
#include <hip/hip_runtime.h>
#include <hip/hip_bf16.h>

typedef unsigned short ushort_t;
typedef __attribute__((ext_vector_type(8))) short short8;
typedef __attribute__((ext_vector_type(4))) short short4v;
typedef __attribute__((ext_vector_type(4))) float f32x4;

// Problem constants
constexpr int Hh = 256, Ww = 256, HW = Hh * Ww;
constexpr int Bb = 2, Cc = 64, Pp = 3, NOo = 16, FEXc = 48, Nn = 32768;
constexpr int TW = 32, TH = 8;       // conv spatial tile per block
constexpr int HALOP = (TH + 2) * 34; // 340 halo pixels
constexpr int AROWS = 352;           // staged act rows (44 DMA x 8 rows)
constexpr int PADH = 72;             // gather-MLP LDS point stride (bf16)

__device__ inline ushort_t f2bf(float v) {
    __hip_bfloat16 h = __float2bfloat16(v);
    return *(ushort_t*)&h;
}
__device__ inline float bf2f(ushort_t u) {
    __hip_bfloat16 h = *(__hip_bfloat16*)&u;
    return __bfloat162float(h);
}
// async 16B global->LDS DMA: dest = lds base (wave-uniform) + lane*16
__device__ inline void gload_lds16(const ushort_t* g, ushort_t* l) {
    __builtin_amdgcn_global_load_lds(
        (const __attribute__((address_space(1))) unsigned int*)g,
        (__attribute__((address_space(3))) unsigned int*)l, 16, 0, 0);
}

// -------- mask weight: wm = mask / max(avg3x3(mask), 1e-8); also zero the zpage ------
__global__ __launch_bounds__(256) void k_wm(const float* __restrict__ mask,
                                            float* __restrict__ wm,
                                            float* __restrict__ zpage) {
    int pos = blockIdx.x * 256 + threadIdx.x;
    if (blockIdx.x == 0 && threadIdx.x < 64) zpage[threadIdx.x] = 0.f;  // 256B zeros
    int h = pos >> 8, w = pos & 255;
    float s = 0.f;
    #pragma unroll
    for (int dy = -1; dy <= 1; ++dy)
        #pragma unroll
        for (int dx = -1; dx <= 1; ++dx) {
            int hh = h + dy, ww = w + dx;
            if (hh >= 0 && hh < Hh && ww >= 0 && ww < Ww) s += mask[hh * Ww + ww];
        }
    float avg = s * (1.f / 9.f);
    wm[pos] = mask[pos] / fmaxf(avg, 1e-8f);
}

// ---------------- zero a float4 buffer ----------------
__global__ __launch_bounds__(256) void k_zero(float4* __restrict__ p) {
    p[blockIdx.x * 256 + threadIdx.x] = make_float4(0.f, 0.f, 0.f, 0.f);
}

// ---------------- weight transforms: fp32 [oc][cin][3][3] -> bf16 [tap][oc][c64] ----
__global__ __launch_bounds__(256) void k_wx_res(const float* __restrict__ src,
                                                ushort_t* __restrict__ dst) {
    int idx = blockIdx.x * 256 + threadIdx.x;          // < 12*9*64*64 = 442368
    int j = idx / 36864; int rem = idx - j * 36864;
    int t = rem >> 12; int o = (rem >> 6) & 63; int c = rem & 63;
    dst[idx] = f2bf(src[j * 36864 + o * 576 + c * 9 + t]);
}
__global__ __launch_bounds__(256) void k_wx_out(const float* __restrict__ src,
                                                ushort_t* __restrict__ dst) {
    int idx = blockIdx.x * 256 + threadIdx.x;          // < 3*9*16*64 = 27648
    int i = idx / 9216; int rem = idx - i * 9216;
    int t = rem >> 10; int o = (rem >> 6) & 15; int c = rem & 63;
    dst[idx] = f2bf(src[i * 9216 + o * 576 + c * 9 + t]);
}
__global__ __launch_bounds__(256) void k_wx_trunk(const float* __restrict__ src,
                                                  ushort_t* __restrict__ dst) {
    int idx = blockIdx.x * 256 + threadIdx.x;          // < 4*9*48*64 = 110592
    int j = idx / 27648; int rem = idx - j * 27648;
    int t = rem / 3072; int rem2 = rem - t * 3072;
    int o = rem2 >> 6; int c = rem2 & 63;
    float v = (c < 48) ? src[j * (48 * 48 * 9) + o * 432 + c * 9 + t] : 0.f;
    dst[idx] = f2bf(v);
}
// MLP weights -> A-frag layout [out][k64] bf16, biases folded at k=49 (L1) / 48 (L2) / 49 (L3)
__global__ __launch_bounds__(256) void k_wx_mlp(
    const float* __restrict__ w1, const float* __restrict__ b1,
    const float* __restrict__ w2, const float* __restrict__ b2,
    const float* __restrict__ w3, const float* __restrict__ b3,
    ushort_t* __restrict__ dst) {
    int idx = blockIdx.x * 256 + threadIdx.x;          // < 7168
    float v = 0.f;
    if (idx < 3072) {                                  // wA1 [48][64]
        int o = idx >> 6, c = idx & 63;
        v = (c < 49) ? w1[o * 49 + c] : (c == 49 ? b1[o] : 0.f);
    } else if (idx < 6144) {                           // wA2 [48][64]
        int o = (idx - 3072) >> 6, c = idx & 63;
        v = (c < 48) ? w2[o * 48 + c] : (c == 48 ? b2[o] : 0.f);
    } else {                                           // wA3 [16][64]
        int o = (idx - 6144) >> 6, c = idx & 63;
        if (o < 3) v = (c < 48) ? w3[o * 48 + c] : (c == 49 ? b3[o] : 0.f);
    }
    dst[idx] = f2bf(v);
}

// ------- xs: NCHW fp32 -> masked NHWC bf16, all pyramids (z = i*B + b) --------------
__global__ __launch_bounds__(256) void k_xm(const float* __restrict__ xs,
                                            const float* __restrict__ mask,
                                            ushort_t* __restrict__ X) {
    __shared__ float l[64 * 65];
    const int p0 = blockIdx.x * 64;
    const size_t zoff = (size_t)blockIdx.y * 64 * HW;
    const int tid = threadIdx.x;
    const int px = tid & 63;
    const float mv = mask[p0 + px];
    #pragma unroll
    for (int k = 0; k < 16; ++k) {
        int c = (tid >> 6) + 4 * k;
        l[c * 65 + px] = xs[zoff + (size_t)c * HW + p0 + px] * mv;
    }
    __syncthreads();
    #pragma unroll
    for (int k = 0; k < 2; ++k) {
        int idx = tid + k * 256;
        int p = idx >> 3, c8 = idx & 7;
        short8 v;
        #pragma unroll
        for (int i = 0; i < 8; ++i) v[i] = (short)f2bf(l[(c8 * 8 + i) * 65 + p]);
        *(short8*)&X[zoff + (size_t)(p0 + p) * 64 + c8 * 8] = v;
    }
}

// ---------------- MFMA implicit-GEMM 3x3 conv (NHWC bf16, ch stride 64) ------------
// TH=8 tile, 4 waves, wave wv owns rows 2wv..2wv+1 (NF=4 frags: row x 2 col-halves).
// Dynamic LDS: act halo (352 rows x 128B = 44KB) staged ONCE, 8-slot XOR swizzle;
// weights per 32-ch K-phase (9*OC x 64B), restaged between phases (L2-resident),
// 4-slot XOR swizzle r = j ^ ((r^(r>>2))&3). OOB act lanes DMA from zero page.
// z = pyramid*2 + batch (trunk: z=batch, wstride=0). TOF: out -> F at chan (z>>1)*16.
// MODE 0: out = relu(conv*wm)    MODE 1: out = base + conv*wm    MODE 2: out = conv*wm
template <int OC, int MODE, bool TOF>
__global__ __launch_bounds__(256) void k_mconv(
    const ushort_t* __restrict__ in,
    const ushort_t* __restrict__ wgt, int wstride,
    const float* __restrict__ wm,
    const ushort_t* __restrict__ zp,      // >=256B of zeros, 16B aligned
    const ushort_t* __restrict__ base,
    ushort_t* __restrict__ out) {
    constexpr int NM = OC / 16;
    constexpr int WROWS = 9 * OC;         // weight rows per phase (32 ch = 64B each)
    constexpr int WDMA = WROWS / 16;      // 1KB DMA instructions per phase
    extern __shared__ __align__(1024) ushort_t smem[];
    ushort_t* alds = smem;                // AROWS*64 elems (45056 B)
    ushort_t* wlds = smem + AROWS * 64;   // WROWS*32 elems
    const int tid = threadIdx.x;
    const int wv = tid >> 6;
    const int ln = tid & 63;
    const int w0 = blockIdx.x * TW, h0 = blockIdx.y * TH;
    const int zz = blockIdx.z;
    const ushort_t* inb = in + (size_t)zz * HW * 64;
    const ushort_t* wB = wgt + (size_t)(zz >> 1) * wstride;
    const ushort_t* baseb = base ? base + (size_t)zz * HW * 64 : nullptr;
    ushort_t* outb = TOF ? out + (size_t)(zz & 1) * HW * 64 : out + (size_t)zz * HW * 64;
    const int ocb = TOF ? (zz >> 1) * 16 : 0;

    const int lo = ln & 15, slr = ln >> 4, g8 = slr * 8;

    f32x4 acc[NM][4];
    #pragma unroll
    for (int mf = 0; mf < NM; ++mf)
        #pragma unroll
        for (int nf = 0; nf < 4; ++nf) acc[mf][nf] = (f32x4){0.f, 0.f, 0.f, 0.f};

    // ---- stage activations once: 11 DMA per wave (8 rows x 128B each) ----
    #pragma unroll
    for (int k = 0; k < 11; ++k) {
        int s = wv * 11 + k;                   // 0..43
        int pp = s * 8 + (ln >> 3);            // 0..351
        int r = (pp * 241) >> 13;              // pp/34 for pp<352
        int col = pp - r * 34;
        int gh = h0 + r - 1, gw = w0 + col - 1;
        bool ok = (pp < HALOP) & (gh >= 0) & (gh < Hh) & (gw >= 0) & (gw < Ww);
        int che = ((ln & 7) ^ (pp & 7)) << 3;  // element offset of 16B chunk
        const ushort_t* src = ok ? inb + (size_t)(gh * Ww + gw) * 64 + che : zp + che;
        gload_lds16(src, &alds[s * 512]);
    }

    #pragma unroll
    for (int h = 0; h < 2; ++h) {
        if (h) __syncthreads();            // all waves done reading wlds phase 0
        // ---- stage weights for this 32-ch K-phase ----
        #pragma unroll
        for (int k = 0; k < (WDMA + 3) / 4; ++k) {
            int s = wv + 4 * k;
            if (s < WDMA) {
                int r = s * 16 + (ln >> 2);        // weight row (tap*OC + oc)
                int d = ln & 3;
                int j = d ^ ((r ^ (r >> 2)) & 3);  // global 16B chunk for this slot
                gload_lds16(wB + (size_t)r * 64 + h * 32 + j * 8, &wlds[s * 512]);
            }
        }
        asm volatile("s_waitcnt vmcnt(0)" ::: "memory");
        __syncthreads();

        // ---- compute this K-phase: 9 taps x NM x 4 MFMA per wave ----
        #pragma unroll
        for (int dy = 0; dy < 3; ++dy)
            #pragma unroll
            for (int dx = 0; dx < 3; ++dx) {
                const int t = dy * 3 + dx;
                short8 bfr[4];
                #pragma unroll
                for (int nf = 0; nf < 4; ++nf) {
                    int pp2 = (2 * wv + (nf >> 1) + dy) * 34 + (nf & 1) * 16 + lo + dx;
                    bfr[nf] = *(const short8*)
                        &alds[pp2 * 64 + (((h * 4 + slr) ^ (pp2 & 7)) << 3)];
                }
                short8 afr[NM];
                #pragma unroll
                for (int mf = 0; mf < NM; ++mf) {
                    int r = t * OC + mf * 16 + lo;
                    afr[mf] = *(const short8*)
                        &wlds[r * 32 + ((slr ^ ((r ^ (r >> 2)) & 3)) << 3)];
                }
                #pragma unroll
                for (int mf = 0; mf < NM; ++mf)
                    #pragma unroll
                    for (int nf = 0; nf < 4; ++nf)
                        acc[mf][nf] = __builtin_amdgcn_mfma_f32_16x16x32_bf16(
                            afr[mf], bfr[nf], acc[mf][nf], 0, 0, 0);
            }
    }

    // ---- epilogue: C col=lane&15 (pixel), row=(lane>>4)*4+j (outch); NHWC 8B stores ----
    #pragma unroll
    for (int nf = 0; nf < 4; ++nf) {
        int r = h0 + 2 * wv + (nf >> 1);
        int x = w0 + (nf & 1) * 16 + lo;
        int pos = r * Ww + x;
        float wmv = wm[pos];
        #pragma unroll
        for (int mf = 0; mf < NM; ++mf) {
            int o0 = ocb + mf * 16 + slr * 4;
            size_t oi = (size_t)pos * 64 + o0;
            float v[4];
            #pragma unroll
            for (int j = 0; j < 4; ++j) v[j] = acc[mf][nf][j] * wmv;
            if (MODE == 0) {
                #pragma unroll
                for (int j = 0; j < 4; ++j) v[j] = fmaxf(v[j], 0.f);
            } else if (MODE == 1) {
                short4v bv = *(const short4v*)&baseb[oi];
                #pragma unroll
                for (int j = 0; j < 4; ++j) v[j] += bf2f((ushort_t)bv[j]);
            }
            short4v sv;
            #pragma unroll
            for (int j = 0; j < 4; ++j) sv[j] = (short)f2bf(v[j]);
            *(short4v*)&outb[oi] = sv;
        }
    }
}

// ---------------- gather + MLP via MFMA: 64 pts/block, 16 pts/wave --------------------
__global__ __launch_bounds__(256) void k_gather_mlp(
    const ushort_t* __restrict__ F, const ushort_t* __restrict__ G,
    const int* __restrict__ yi, const float* __restrict__ m,
    const ushort_t* __restrict__ wA1, const ushort_t* __restrict__ wA2,
    const ushort_t* __restrict__ wA3, float* __restrict__ pvd) {
    __shared__ __align__(16) ushort_t HA[4 * 16 * PADH];
    __shared__ __align__(16) ushort_t HB[4 * 16 * PADH];
    const int tid = threadIdx.x, wv = tid >> 6, ln = tid & 63;
    ushort_t* ha = HA + wv * 16 * PADH;
    ushort_t* hb = HB + wv * 16 * PADH;
    const int t0 = blockIdx.x * 64 + wv * 16;
    const int b = t0 >> 15;
    const int lo = ln & 15, g8 = (ln >> 4) * 8;

    #pragma unroll
    for (int rnd = 0; rnd < 2; ++rnd) {
        int j = rnd * 64 + ln;
        if (j < 96) {
            int pt = j / 6, sl = j - pt * 6;
            int n = (t0 + pt) & (Nn - 1);
            int pos = yi[n];
            size_t gi = ((size_t)(b * HW) + pos) * 64 + sl * 8;
            short8 fa = *(const short8*)&F[gi];
            short8 ga = *(const short8*)&G[gi];
            short8 sv;
            #pragma unroll
            for (int i = 0; i < 8; ++i)
                sv[i] = (short)f2bf(bf2f((ushort_t)fa[i]) + bf2f((ushort_t)ga[i]));
            *(short8*)&ha[pt * PADH + sl * 8] = sv;
        }
    }
    if (ln < 16) {
        int pt = ln;
        int n = (t0 + pt) & (Nn - 1);
        int pos = yi[n];
        float det = m[0] * (m[4] * m[8] - m[5] * m[7])
                  - m[1] * (m[3] * m[8] - m[5] * m[6])
                  + m[2] * (m[3] * m[7] - m[4] * m[6]);
        int yr = pos >> 8, xc = pos & 255;
        float wc = m[6] * (float)xc + m[7] * (float)yr + m[8];
        float cw = fmaxf(fabsf(wc), 1e-8f);
        float dsda = fabsf(det) / (cw * cw * cw);
        float ld = logf(dsda + 1e-8f);
        const ushort_t one = f2bf(1.0f);
        short8 z = {0, 0, 0, 0, 0, 0, 0, 0};
        short8 sa = z; sa[0] = (short)f2bf(ld); sa[1] = (short)one;
        short8 sb = z; sb[0] = (short)one;
        *(short8*)&ha[pt * PADH + 48] = sa;
        *(short8*)&ha[pt * PADH + 56] = z;
        *(short8*)&hb[pt * PADH + 48] = sb;
        *(short8*)&hb[pt * PADH + 56] = z;
    }
    asm volatile("s_waitcnt lgkmcnt(0)" ::: "memory");

    f32x4 a1[3] = {{0.f,0.f,0.f,0.f},{0.f,0.f,0.f,0.f},{0.f,0.f,0.f,0.f}};
    #pragma unroll
    for (int ks = 0; ks < 2; ++ks) {
        short8 bf = *(const short8*)&ha[lo * PADH + ks * 32 + g8];
        #pragma unroll
        for (int mf = 0; mf < 3; ++mf) {
            short8 af = *(const short8*)&wA1[(mf * 16 + lo) * 64 + ks * 32 + g8];
            a1[mf] = __builtin_amdgcn_mfma_f32_16x16x32_bf16(af, bf, a1[mf], 0, 0, 0);
        }
    }
    #pragma unroll
    for (int mf = 0; mf < 3; ++mf) {
        short4v sv;
        #pragma unroll
        for (int j = 0; j < 4; ++j) sv[j] = (short)f2bf(fmaxf(a1[mf][j], 0.f));
        *(short4v*)&hb[lo * PADH + mf * 16 + (ln >> 4) * 4] = sv;
    }
    asm volatile("s_waitcnt lgkmcnt(0)" ::: "memory");

    f32x4 a2[3] = {{0.f,0.f,0.f,0.f},{0.f,0.f,0.f,0.f},{0.f,0.f,0.f,0.f}};
    #pragma unroll
    for (int ks = 0; ks < 2; ++ks) {
        short8 bf = *(const short8*)&hb[lo * PADH + ks * 32 + g8];
        #pragma unroll
        for (int mf = 0; mf < 3; ++mf) {
            short8 af = *(const short8*)&wA2[(mf * 16 + lo) * 64 + ks * 32 + g8];
            a2[mf] = __builtin_amdgcn_mfma_f32_16x16x32_bf16(af, bf, a2[mf], 0, 0, 0);
        }
    }
    #pragma unroll
    for (int mf = 0; mf < 3; ++mf) {
        short4v sv;
        #pragma unroll
        for (int j = 0; j < 4; ++j) sv[j] = (short)f2bf(fmaxf(a2[mf][j], 0.f));
        *(short4v*)&ha[lo * PADH + mf * 16 + (ln >> 4) * 4] = sv;
    }
    asm volatile("s_waitcnt lgkmcnt(0)" ::: "memory");

    f32x4 a3 = {0.f, 0.f, 0.f, 0.f};
    #pragma unroll
    for (int ks = 0; ks < 2; ++ks) {
        short8 bf = *(const short8*)&ha[lo * PADH + ks * 32 + g8];
        short8 af = *(const short8*)&wA3[lo * 64 + ks * 32 + g8];
        a3 = __builtin_amdgcn_mfma_f32_16x16x32_bf16(af, bf, a3, 0, 0, 0);
    }
    if (ln < 16) {
        int n = (t0 + lo) & (Nn - 1);
        int pos = yi[n];
        #pragma unroll
        for (int j = 0; j < 3; ++j)
            pvd[(size_t)(b * Pp + j) * HW + pos] = a3[j];
    }
}

// ---------------- out[b,c,pos] = sum_p pvd[b,p,pos] * xs[p,b,c,pos] ----------------
__global__ __launch_bounds__(256) void k_blend(const float4* __restrict__ xs,
                                               const float4* __restrict__ pvd,
                                               float4* __restrict__ out) {
    int i = blockIdx.x * 256 + threadIdx.x;   // over B*C*HW/4
    int pos4 = i & (HW / 4 - 1);
    int bc = i >> 14;
    int b = bc >> 6;
    float4 acc = make_float4(0.f, 0.f, 0.f, 0.f);
    #pragma unroll
    for (int p = 0; p < Pp; ++p) {
        float4 pv = pvd[(b * Pp + p) * (HW / 4) + pos4];
        float4 x = xs[p * (Bb * Cc * HW / 4) + i];
        acc.x += pv.x * x.x;
        acc.y += pv.y * x.y;
        acc.z += pv.z * x.z;
        acc.w += pv.w * x.w;
    }
    out[i] = acc;
}

extern "C" void kernel_launch(void* const* d_in, const int* in_sizes, int n_in,
                              void* d_out, int out_size, void* d_ws, size_t ws_size,
                              hipStream_t stream) {
    const float* xs        = (const float*)d_in[0];
    const float* mask      = (const float*)d_in[1];
    const int*   yi        = (const int*)d_in[2];
    const float* m         = (const float*)d_in[3];
    const float* ss_res_w  = (const float*)d_in[4];
    const float* ss_out_w  = (const float*)d_in[5];
    const float* feat_res_w= (const float*)d_in[6];
    const float* w1 = (const float*)d_in[7];
    const float* b1 = (const float*)d_in[8];
    const float* w2 = (const float*)d_in[9];
    const float* b2 = (const float*)d_in[10];
    const float* w3 = (const float*)d_in[11];
    const float* b3 = (const float*)d_in[12];

    // ws: wm f32 | zpage (64 f32) | pvd f32 | wB | wA | X (P,B,HW,64) | U | V | F | G
    float* wm    = (float*)d_ws;
    float* zpage = wm + HW;
    float* pvd   = zpage + 64;
    ushort_t* wB = (ushort_t*)(pvd + (size_t)Bb * Pp * HW);
    constexpr size_t RES_T = 12 * 9 * 64 * 64;     // 442368
    constexpr size_t OUT_T = 3 * 9 * 16 * 64;      // 27648
    constexpr size_t TRK_T = 4 * 9 * 48 * 64;      // 110592
    constexpr size_t MLP_T = 7168;
    constexpr size_t ZT = (size_t)Pp * Bb * HW * 64;   // 25165824
    ushort_t* wA = wB + RES_T + OUT_T + TRK_T;
    ushort_t* X = wA + MLP_T;
    ushort_t* U = X + ZT;
    ushort_t* V = U + ZT;
    ushort_t* F = V + ZT;
    ushort_t* G = F + (size_t)Bb * HW * 64;
    const ushort_t* zp = (const ushort_t*)zpage;

    k_wm<<<HW / 256, 256, 0, stream>>>(mask, wm, zpage);
    k_wx_res  <<<RES_T / 256, 256, 0, stream>>>(ss_res_w, wB);
    k_wx_out  <<<OUT_T / 256, 256, 0, stream>>>(ss_out_w, wB + RES_T);
    k_wx_trunk<<<TRK_T / 256, 256, 0, stream>>>(feat_res_w, wB + RES_T + OUT_T);
    k_wx_mlp  <<<MLP_T / 256, 256, 0, stream>>>(w1, b1, w2, b2, w3, b3, wA);

    const dim3 gridP(Ww / TW, Hh / TH, Pp * Bb);   // (8, 32, 6)
    const dim3 gridT(Ww / TW, Hh / TH, Bb);        // (8, 32, 2)
    const int RS = 4 * 9 * 64 * 64;                // per-pyramid res weight stride
    const int OS = 9 * 16 * 64;                    // per-pyramid out weight stride
    constexpr size_t SH64 = (size_t)AROWS * 128 + 9 * 64 * 64;   // 45056+36864 = 81920
    constexpr size_t SH48 = (size_t)AROWS * 128 + 9 * 48 * 64;   // 72704
    constexpr size_t SH16 = (size_t)AROWS * 128 + 9 * 16 * 64;   // 54272

    k_xm<<<dim3(HW / 64, Pp * Bb), 256, 0, stream>>>(xs, mask, X);
    k_mconv<64, 0, false><<<gridP, 256, SH64, stream>>>(X, wB,             RS, wm, zp, nullptr, U);
    k_mconv<64, 1, false><<<gridP, 256, SH64, stream>>>(U, wB + 1 * 36864, RS, wm, zp, X,       V);
    k_mconv<64, 0, false><<<gridP, 256, SH64, stream>>>(V, wB + 2 * 36864, RS, wm, zp, nullptr, U);
    k_mconv<64, 1, false><<<gridP, 256, SH64, stream>>>(U, wB + 3 * 36864, RS, wm, zp, V,       V);
    k_mconv<16, 2, true ><<<gridP, 256, SH16, stream>>>(V, wB + RES_T,     OS, wm, zp, nullptr, F);

    const ushort_t* tw = wB + RES_T + OUT_T;
    k_mconv<48, 0, false><<<gridT, 256, SH48, stream>>>(F, tw,             0, wm, zp, nullptr, U);
    k_mconv<48, 1, false><<<gridT, 256, SH48, stream>>>(U, tw + 1 * 27648, 0, wm, zp, F,       G);
    k_mconv<48, 0, false><<<gridT, 256, SH48, stream>>>(G, tw + 2 * 27648, 0, wm, zp, nullptr, U);
    k_mconv<48, 1, false><<<gridT, 256, SH48, stream>>>(U, tw + 3 * 27648, 0, wm, zp, G,       G);

    k_zero<<<(Bb * Pp * HW / 4) / 256, 256, 0, stream>>>((float4*)pvd);
    k_gather_mlp<<<Bb * Nn / 64, 256, 0, stream>>>(F, G, yi, m,
        wA, wA + 3072, wA + 6144, pvd);
    k_blend<<<(Bb * Cc * HW / 4) / 256, 256, 0, stream>>>((const float4*)xs, (const float4*)pvd,
                                                          (float4*)d_out);
}